// Round 1
// baseline (57.265 us; speedup 1.0000x reference)
//
#include <hip/hip_runtime.h>
#include <hip/hip_bf16.h>

#define SEQ    2048
#define NHEAD  16
#define RPH    512          // rows per head = B*D
#define BM     128
#define BN     128
#define BK     64
#define NTH    256

#define WSTRIDE 2184        // elems per wrev copy; 2184 % 64 == 8 (bank spread)
#define WBASE_N 2176        // reversed-w staging elems (2048 + 128 zero pad)
#define ABUF_B  (BM * BK * 2)             // 16384 bytes
#define LDS_B   (ABUF_B + 8 * WSTRIDE * 2)  // 16384 + 34944 = 51328

typedef float  f32x4  __attribute__((ext_vector_type(4)));
typedef __bf16 bf16x8 __attribute__((ext_vector_type(8)));

__device__ __forceinline__ unsigned short f2bf(float f) {
    union { __hip_bfloat16 h; unsigned short u; } cv;
    cv.h = __float2bfloat16(f);
    return cv.u;
}

__global__ __launch_bounds__(NTH, 3) void mixer_kernel(
    const float* __restrict__ x, const float* __restrict__ wgt,
    const float* __restrict__ bias, float* __restrict__ out)
{
    __shared__ char smem[LDS_B] __attribute__((aligned(16)));
    char* abuf = smem;                      // A tile (bf16, swizzled)
    unsigned short* wbase = (unsigned short*)smem;  // temp alias (pre-loop only)
    char* wcop = smem + ABUF_B;             // 8 shifted reversed-w copies

    const int tid  = threadIdx.x;
    const int lane = tid & 63;
    const int wv   = tid >> 6;

    // ---- block decode: XCD-affine heads, descending-K col tiles first ----
    const int bid  = blockIdx.x;            // 0..1023
    const int rest = bid >> 3;               // 0..127
    const int m    = (bid & 7) + 8 * (rest & 1);
    const int r2   = rest >> 1;               // 0..63
    const int rt   = r2 & 3;                  // row tile 0..3
    const int ct   = 15 - (r2 >> 2);          // col tile, big K dispatched first
    const int t0   = ct * BN;
    const int nch  = 2 * (ct + 1);            // K chunks of 64: s < t0+128

    const float* Xb = x   + (size_t)(m * RPH + rt * BM) * SEQ;
    float*       Ob = out + (size_t)(m * RPH + rt * BM) * SEQ;
    const float* wr = wgt  + m * SEQ;
    const float* br = bias + m * SEQ;

    // ---- phase 1: reversed bf16 weights into LDS: wbase[i] = bf16(w[2047-i]) ----
    {
        const int t8 = tid * 8;              // 0..2040, covers [0,2048) exactly
        const float* g = wr + (2040 - t8);
        float4 lo = *(const float4*)g;       // w[2040-t8 .. 2043-t8]
        float4 hi = *(const float4*)(g + 4); // w[2044-t8 .. 2047-t8]
        uint4 v;
        v.x = f2bf(hi.w) | ((unsigned)f2bf(hi.z) << 16);
        v.y = f2bf(hi.y) | ((unsigned)f2bf(hi.x) << 16);
        v.z = f2bf(lo.w) | ((unsigned)f2bf(lo.z) << 16);
        v.w = f2bf(lo.y) | ((unsigned)f2bf(lo.x) << 16);
        *(uint4*)(smem + t8 * 2) = v;
        if (tid < (WBASE_N - 2048) / 8) {    // 16 threads zero the pad
            uint4 z = {0u, 0u, 0u, 0u};
            *(uint4*)(smem + (2048 + tid * 8) * 2) = z;
        }
    }
    __syncthreads();

    // ---- phase 2: build 8 shifted copies: copy_c[i] = wbase[i-c] (0 outside) ----
    for (int idx = tid; idx < 8 * WSTRIDE; idx += NTH) {
        const int c = idx / WSTRIDE;
        const int i = idx - c * WSTRIDE;
        const int src = i - c;
        unsigned short v = ((unsigned)src < (unsigned)WBASE_N) ? wbase[src]
                                                               : (unsigned short)0;
        *(unsigned short*)(wcop + 2 * idx) = v;
    }
    // NOTE: wbase region (== abuf) must not be overwritten until the loop-top
    // __syncthreads() below has passed for all threads.

    // ---- per-lane constants ----
    const int col_low = lane & 15;
    const int kq      = lane >> 4;
    const int swz     = (lane & 7) << 4;     // == (row&7)<<4 for this lane's A rows
    const int rbase   = (wv & 1) * 64;
    const int cbase   = (wv >> 1) * 64;
    const int cpy     = (col_low + 1) & 7;   // alignment class -> which copy
    // B elem index = Bc0 + s0 + 32*ks - 16*c ; always 8-aligned, >= 0
    const int Bc0 = cpy * WSTRIDE + cpy + 2047 - col_low + 8 * kq - t0 - cbase;

    int Arow[4];
    #pragma unroll
    for (int a = 0; a < 4; ++a)
        Arow[a] = (rbase + a * 16 + col_low) * (BK * 2);

    f32x4 acc[4][4] = {};

    // ---- prefetch chunk 0 into registers ----
    const int srow = tid >> 3;               // 0..31
    const int scol = (tid & 7) * 8;          // 0..56
    float4 pf[8];
    #pragma unroll
    for (int p = 0; p < 4; ++p) {
        const float* g = Xb + (size_t)(p * 32 + srow) * SEQ + scol;
        pf[2 * p]     = *(const float4*)g;
        pf[2 * p + 1] = *(const float4*)(g + 4);
    }
    const int wbyte = (tid & 7) * 16;        // 16B slot before swizzle

    for (int ch = 0; ch < nch; ++ch) {
        const int s0 = ch * BK;
        __syncthreads();   // prev compute done (and, at ch=0, copies built)
        // write staged regs -> abuf as bf16, XOR-swizzled rows
        #pragma unroll
        for (int p = 0; p < 4; ++p) {
            const int row = p * 32 + srow;
            float4 A = pf[2 * p], Bv = pf[2 * p + 1];
            uint4 v;
            v.x = f2bf(A.x)  | ((unsigned)f2bf(A.y)  << 16);
            v.y = f2bf(A.z)  | ((unsigned)f2bf(A.w)  << 16);
            v.z = f2bf(Bv.x) | ((unsigned)f2bf(Bv.y) << 16);
            v.w = f2bf(Bv.z) | ((unsigned)f2bf(Bv.w) << 16);
            *(uint4*)(abuf + row * (BK * 2) + (wbyte ^ ((row & 7) << 4))) = v;
        }
        // issue next chunk's loads early: HBM latency hides under MFMA phase
        if (ch + 1 < nch) {
            #pragma unroll
            for (int p = 0; p < 4; ++p) {
                const float* g = Xb + (size_t)(p * 32 + srow) * SEQ
                                 + (s0 + BK) + scol;
                pf[2 * p]     = *(const float4*)g;
                pf[2 * p + 1] = *(const float4*)(g + 4);
            }
        }
        __syncthreads();   // abuf ready

        #pragma unroll
        for (int ks = 0; ks < 2; ++ks) {
            bf16x8 af[4], bfg[4];
            const int kb = 64 * ks + 16 * kq;
            #pragma unroll
            for (int a = 0; a < 4; ++a)
                af[a] = *(const bf16x8*)(abuf + Arow[a] + (kb ^ swz));
            #pragma unroll
            for (int c = 0; c < 4; ++c) {
                const int e = Bc0 + s0 + 32 * ks - 16 * c;
                bfg[c] = *(const bf16x8*)(wcop + 2 * e);
            }
            #pragma unroll
            for (int a = 0; a < 4; ++a)
                #pragma unroll
                for (int c = 0; c < 4; ++c)
                    acc[a][c] = __builtin_amdgcn_mfma_f32_16x16x32_bf16(
                                    af[a], bfg[c], acc[a][c], 0, 0, 0);
        }
    }

    // ---- epilogue: C/D layout col=lane&15, row=(lane>>4)*4+reg ----
    #pragma unroll
    for (int c = 0; c < 4; ++c) {
        const int colg = t0 + cbase + 16 * c + col_low;
        const float bv = br[colg];
        #pragma unroll
        for (int a = 0; a < 4; ++a) {
            const int rowl = rbase + a * 16 + kq * 4;
            #pragma unroll
            for (int r = 0; r < 4; ++r)
                Ob[(size_t)(rowl + r) * SEQ + colg] = acc[a][c][r] + bv;
        }
    }
}

extern "C" void kernel_launch(void* const* d_in, const int* in_sizes, int n_in,
                              void* d_out, int out_size, void* d_ws, size_t ws_size,
                              hipStream_t stream) {
    const float* x  = (const float*)d_in[0];
    const float* w  = (const float*)d_in[1];
    const float* bs = (const float*)d_in[2];
    float* out = (float*)d_out;
    dim3 grid(NHEAD * 4 * 16);   // 16 heads x 4 row tiles x 16 col tiles = 1024
    dim3 block(NTH);
    hipLaunchKernelGGL(mixer_kernel, grid, block, 0, stream, x, w, bs, out);
}